// Round 6
// baseline (441.500 us; speedup 1.0000x reference)
//
#include <hip/hip_runtime.h>
#include <hip/hip_fp16.h>
#include <stdint.h>

// Problem constants (fixed by the reference)
#define N_ 16384
#define M_ 4096
#define D_ 256
#define O_ 256

// Workspace layout (bytes), total ~2.3 MB
#define WS_T    0          // float[N]      exp(sf+ba)     64 KB
#define WS_U    65536      // float[M]      exp(sc)        16 KB
#define WS_R    81920      // float[D]      colsum(Hc)      1 KB
#define WS_WTP  98304      // ushort        Wt packed f16 128 KB
#define WS_BP   229376     // ushort        Hc packed f16   2 MB

typedef float  f32x4  __attribute__((ext_vector_type(4)));
typedef _Float16 half8 __attribute__((ext_vector_type(8)));

// fp32 -> f16 bits (RNE)
__device__ __forceinline__ unsigned short f2h(float f) {
  __half h = __float2half(f);
  unsigned short u;
  __builtin_memcpy(&u, &h, 2);
  return u;
}
// pack two fp32 -> f16x2 bits
__device__ __forceinline__ uint32_t hpack(float a, float b) {
  __half2 h = __floats2half2_rn(a, b);
  uint32_t u;
  __builtin_memcpy(&u, &h, 4);
  return u;
}

// ---------------------------------------------------------------------------
// Merged prep: blocks [0,4096) rowdot(Hf)->tv, [4096,5120) rowdot(Hc)->uv,
// [5120,5376) hc_pack (BP f16 + colsum->Rv atomics), [5376,5408) wt_pack f16.
__global__ __launch_bounds__(256) void prep_kernel(
    const float* __restrict__ Hf, const float* __restrict__ Hc,
    const float* __restrict__ wa, const float* __restrict__ ba,
    const float* __restrict__ Wt, float* __restrict__ tv,
    float* __restrict__ uv, unsigned short* __restrict__ BP,
    unsigned short* __restrict__ WtP, float* __restrict__ Rv) {
  __shared__ float tile[64][65];
  __shared__ float red[4][64];
  int b = blockIdx.x;
  int t = threadIdx.x;
  if (b < 5120) {
    // ---- rowdot_exp: per-row dot with weight half, then exp(dot + bias)
    int wv = t >> 6, lane = t & 63;
    const float* X; const float* w; const float* bias; float* outv; int row;
    if (b < 4096) { X = Hf; w = wa;      bias = ba;      outv = tv; row = b * 4 + wv; }
    else          { X = Hc; w = wa + D_; bias = nullptr; outv = uv; row = (b - 4096) * 4 + wv; }
    const float4* x4 = (const float4*)(X + (size_t)row * D_);
    const float4* w4 = (const float4*)w;
    float4 xa = x4[lane], wa4 = w4[lane];
    float s = xa.x * wa4.x + xa.y * wa4.y + xa.z * wa4.z + xa.w * wa4.w;
#pragma unroll
    for (int off = 32; off > 0; off >>= 1) s += __shfl_xor(s, off);
    if (lane == 0) outv[row] = expf(s + (bias ? bias[0] : 0.0f));
  } else if (b < 5376) {
    // ---- hc_pack: Hc [M,D] fp32 -> BP fragment-major f16 + colsum.
    // BP[((kg*16+cg)*64+lane)*8+j] = f16(Hc[kg*32+q*8+j][cg*16+m]), lane=q*16+m.
    int bb = b - 5120;
    int bk = bb >> 2;   // 64 tiles along M (k)
    int bc = bb & 3;    // 4 tiles along D (col)
    int k0 = bk * 64, col0 = bc * 64;
    int lane = t & 63, wv = t >> 6;
    int m = lane & 15, q = lane >> 4;
    float colsum = 0.0f;
#pragma unroll
    for (int i = 0; i < 16; ++i) {
      int e = t + 256 * i;
      int kk = e >> 6, cc = e & 63;
      float v = Hc[(size_t)(k0 + kk) * D_ + col0 + cc];
      tile[kk][cc] = v;
      colsum += v;
    }
    red[wv][t & 63] = colsum;
    __syncthreads();
    if (t < 64)
      atomicAdd(&Rv[col0 + t], red[0][t] + red[1][t] + red[2][t] + red[3][t]);
#pragma unroll
    for (int t8 = 0; t8 < 2; ++t8) {
      int tile_id = t8 * 4 + wv;
      int sub = tile_id >> 2, g = tile_id & 3;
      int kgg = bk * 2 + sub;
      int cgg = bc * 4 + g;
      unsigned short v8[8];
#pragma unroll
      for (int j = 0; j < 8; ++j)
        v8[j] = f2h(tile[sub * 32 + q * 8 + j][g * 16 + m]);
      *(uint4*)(BP + ((size_t)(kgg * 16 + cgg) * 64 + lane) * 8) = *(uint4*)v8;
    }
  } else {
    // ---- wt_pack: Wt [O,D] fp32 -> WtP fragment-major f16
    int tt = (b - 5376) * 256 + t;    // 0..8191
    int lane = tt & 63, cg = (tt >> 6) & 15, kg = tt >> 10;
    int m = lane & 15, q = lane >> 4;
    const float* src = Wt + (size_t)(cg * 16 + m) * D_ + kg * 32 + q * 8;
    float4 w0 = *(const float4*)src, w1 = *(const float4*)(src + 4);
    unsigned short v8[8];
    v8[0] = f2h(w0.x); v8[1] = f2h(w0.y); v8[2] = f2h(w0.z); v8[3] = f2h(w0.w);
    v8[4] = f2h(w1.x); v8[5] = f2h(w1.y); v8[6] = f2h(w1.z); v8[7] = f2h(w1.w);
    *(uint4*)(WtP + (size_t)tt * 8) = *(uint4*)v8;
  }
}

// ---------------------------------------------------------------------------
// Build an f16 MFMA A-fragment from 8 adj bits: slot j = bit_j ? (t*u_j - 1) : 0.
// One v_pk_fma_f16 per pair (t,u pre-packed half2); mask via BFE/BFI idioms.
// Masking with 0x0000 yields exact +0.0.
__device__ __forceinline__ half8 frag_f16(uint32_t bits, __half2 th,
                                          const __half2* up, __half2 mone) {
  union { half8 h; uint32_t u[4]; } r;
#pragma unroll
  for (int p = 0; p < 4; ++p) {
    __half2 v = __hfma2(th, up[p], mone);
    uint32_t c;
    __builtin_memcpy(&c, &v, 4);
    uint32_t mlo = (uint32_t)((int32_t)(bits << (31 - 2 * p)) >> 31);
    uint32_t mhi = (uint32_t)((int32_t)(bits << (30 - 2 * p)) >> 31);
    r.u[p] = c & ((mlo & 0x0000FFFFu) | (mhi & 0xFFFF0000u));   // v_bfi
  }
  return r.h;
}

// one f16 kstep for 2 row-tiles x 4 col-groups
#define COMPUTE_K(WB0, WB1, KK, BUF)                                          \
  {                                                                           \
    uint4 uu = *(const uint4*)&u_h2[(KK) * 16 + q * 4];                       \
    __half2 up[4];                                                            \
    __builtin_memcpy(up, &uu, 16);                                            \
    half8 af = frag_f16(((WB0) >> sh) & 0xffu, th0, up, mone);                \
    _Pragma("unroll")                                                         \
    for (int n = 0; n < 4; ++n)                                               \
      acc[0][n] = __builtin_amdgcn_mfma_f32_16x16x32_f16(af, BUF[n], acc[0][n], 0, 0, 0); \
    af = frag_f16(((WB1) >> sh) & 0xffu, th1, up, mone);                      \
    _Pragma("unroll")                                                         \
    for (int n = 0; n < 4; ++n)                                               \
      acc[1][n] = __builtin_amdgcn_mfma_f32_16x16x32_f16(af, BUF[n], acc[1][n], 0, 0, 0); \
  }

// ---------------------------------------------------------------------------
// Mega kernel v4: 32-row blocks, 512 thr (8 waves = 4 colq x 2 ksub),
// grid 512 -> 2 blocks/CU. Rationale (R5 counters): 1 block/CU serialized
// prologue (memory) -> K-loop (issue/latency) -> epilogue with ~60 us of
// unfilled stalls (VALUBusy 27%, MfmaUtil 9%, hbm 14%). Two co-resident
// blocks sit in different phases and co-schedule MFMA/VALU/memory pipes.
// Prologue: 4 rows/wave interleaved (4 KB in flight/wave, 64 KB/CU).
// K-loop: per wave 2 row-tiles x 4 col-groups x 64 ksteps, depth-1 B dbuf.
// LDS: bt2[32][132] 16.9K | u_f32 16K | u_h2 8K | Cred[32][260] 33.3K |
//      Lsum .13K = 74.9 KB -> 2 blocks/CU (149.8 <= 160 KB).
__global__ __launch_bounds__(512, 4) void mega_kernel(
    const float* __restrict__ adj, const unsigned short* __restrict__ BP,
    const float* __restrict__ tv, const float* __restrict__ uv,
    const float* __restrict__ Rv, const float* __restrict__ Hf,
    const unsigned short* __restrict__ WtP, const float* __restrict__ bt,
    float* __restrict__ out) {
  __shared__ __align__(16) char smem[74880];
  unsigned int (*bt2)[132] = (unsigned int (*)[132])(smem);           // 16896 B
  float* u_lds = (float*)(smem + 16896);                              // 16384 B
  uint32_t* u_h2 = (uint32_t*)(smem + 33280);                         //  8192 B
  float (*Cred)[260] = (float (*)[260])(smem + 41472);                // 33280 B
  float* Lsum_lds = (float*)(smem + 74752);                           //   128 B
  unsigned short (*attn)[264] = (unsigned short (*)[264])(smem);      // 16896 B (aliases bt2, dead by then)

  int tid = threadIdx.x;
  int w = tid >> 6, lane = tid & 63;
  int q = lane >> 4, m = lane & 15;
  int colq = w >> 1, ksub = w & 1;
  int i0 = blockIdx.x * 32;

  // u: f32 copy (prologue) + packed half2 copy (K-loop)
  for (int i = tid; i < M_ / 2; i += 512) {
    float2 u2 = *(const float2*)(uv + 2 * i);
    u_lds[2 * i] = u2.x; u_lds[2 * i + 1] = u2.y;
    u_h2[i] = hpack(u2.x, u2.y);
  }
  __syncthreads();  // u ready (prologue needs it for Lsum fmas)

  // ---- Prologue: adj -> bits in LDS + Lsum. Wave w owns rows w*4..w*4+3,
  // all 4 streamed interleaved with depth-1 prefetch (4 KB/wave in flight).
  {
    int r0 = w * 4;
    const float* ar = adj + ((size_t)i0 + r0) * M_;
    float su[4] = {0.f, 0.f, 0.f, 0.f}, sc[4] = {0.f, 0.f, 0.f, 0.f};
    float a[4][4], na[4][4];
#pragma unroll
    for (int j = 0; j < 4; ++j)
#pragma unroll
      for (int c = 0; c < 4; ++c)
        a[j][c] = ar[(size_t)j * M_ + c * 64 + lane];
#pragma unroll 1
    for (int i = 0; i < 16; ++i) {
      int k0 = i * 256;
      int k1 = (i + 1 < 16) ? k0 + 256 : 0;     // wrap: harmless reload
#pragma unroll
      for (int j = 0; j < 4; ++j)
#pragma unroll
        for (int c = 0; c < 4; ++c)
          na[j][c] = ar[(size_t)j * M_ + k1 + c * 64 + lane];
      unsigned long long bal[4][4];
#pragma unroll
      for (int j = 0; j < 4; ++j) {
#pragma unroll
        for (int c = 0; c < 4; ++c) {
          bal[j][c] = __ballot(a[j][c] != 0.0f);
          su[j] = fmaf(a[j][c], u_lds[k0 + c * 64 + lane], su[j]);
        }
        sc[j] += (a[j][0] + a[j][1]) + (a[j][2] + a[j][3]);
      }
      if (lane < 32) {
        int rowsel = lane >> 3;                 // 0..3
        int c = (lane >> 1) & 3, hi = lane & 1;
        unsigned long long v0 = (c == 0) ? bal[0][0] : (c == 1) ? bal[0][1] : (c == 2) ? bal[0][2] : bal[0][3];
        unsigned long long v1 = (c == 0) ? bal[1][0] : (c == 1) ? bal[1][1] : (c == 2) ? bal[1][2] : bal[1][3];
        unsigned long long v2 = (c == 0) ? bal[2][0] : (c == 1) ? bal[2][1] : (c == 2) ? bal[2][2] : bal[2][3];
        unsigned long long v3 = (c == 0) ? bal[3][0] : (c == 1) ? bal[3][1] : (c == 2) ? bal[3][2] : bal[3][3];
        unsigned long long v = (rowsel == 0) ? v0 : (rowsel == 1) ? v1 : (rowsel == 2) ? v2 : v3;
        bt2[r0 + rowsel][i * 8 + c * 2 + hi] =
            hi ? (unsigned int)(v >> 32) : (unsigned int)v;
      }
#pragma unroll
      for (int j = 0; j < 4; ++j)
#pragma unroll
        for (int c = 0; c < 4; ++c) a[j][c] = na[j][c];
    }
#pragma unroll
    for (int off = 32; off > 0; off >>= 1) {
#pragma unroll
      for (int j = 0; j < 4; ++j) {
        su[j] += __shfl_xor(su[j], off);
        sc[j] += __shfl_xor(sc[j], off);
      }
    }
    if (lane == 0) {
#pragma unroll
      for (int j = 0; j < 4; ++j)
        Lsum_lds[r0 + j] = tv[i0 + r0 + j] * su[j] - sc[j];
    }
  }

  // B base + first-kstep prefetch (no LDS dep; overlaps the barrier)
  const unsigned short* bbase = BP + (size_t)(colq * 4) * 512 + (size_t)lane * 8;
  int kg0 = ksub * 64;
  half8 bufA[4], bufB[4];
#pragma unroll
  for (int n = 0; n < 4; ++n)
    bufA[n] = *(const half8*)(bbase + ((size_t)kg0 * 16 + n) * 512);

  __half2 th0 = __float2half2_rn(tv[i0 + m]);
  __half2 th1 = __float2half2_rn(tv[i0 + 16 + m]);
  const __half2 mone = __float2half2_rn(-1.0f);

  f32x4 acc[2][4];
#pragma unroll
  for (int s = 0; s < 2; ++s)
#pragma unroll
    for (int n = 0; n < 4; ++n) acc[s][n] = (f32x4){0.f, 0.f, 0.f, 0.f};

  __syncthreads();  // bits + Lsum ready

#pragma unroll 1
  for (int it2 = 0; it2 < 32; ++it2) {
    int kg = kg0 + it2 * 2;
    // bits for 2 ksteps x 2 row-tiles: one ds_read_b64 each (conflict-free)
    uint2 W0 = *(const uint2*)&bt2[m][kg];
    uint2 W1 = *(const uint2*)&bt2[16 + m][kg];
    int sh = q * 8;

    // ---- kstep kg (bufA); prefetch kg+1 into bufB
#pragma unroll
    for (int n = 0; n < 4; ++n)
      bufB[n] = *(const half8*)(bbase + ((size_t)(kg + 1) * 16 + n) * 512);
    COMPUTE_K(W0.x, W1.x, kg, bufA)

    // ---- kstep kg+1 (bufB); prefetch kg+2 into bufA (wrap: harmless reload)
    int kn = (it2 + 1 < 32) ? kg + 2 : kg0;
#pragma unroll
    for (int n = 0; n < 4; ++n)
      bufA[n] = *(const half8*)(bbase + ((size_t)kn * 16 + n) * 512);
    COMPUTE_K(W0.y, W1.y, kg + 1, bufB)
  }

  // ---- Phase 2: sequential ksub-plane reduction into fp32 Cred (exact)
#pragma unroll
  for (int s4 = 0; s4 < 2; ++s4) {
    if (ksub == s4) {
#pragma unroll
      for (int s = 0; s < 2; ++s)
#pragma unroll
        for (int n = 0; n < 4; ++n) {
          int col = colq * 64 + n * 16 + m;
#pragma unroll
          for (int r = 0; r < 4; ++r) {
            int rl = s * 16 + q * 4 + r;     // C/D: row=(lane>>4)*4+reg
            if (s4 == 0) Cred[rl][col] = acc[s][n][r];
            else         Cred[rl][col] += acc[s][n][r];
          }
        }
    }
    __syncthreads();
  }

  // ---- Phase 3a: attn = (Cred + R)/(Lsum + M) + Hf -> f16 LDS
  {
    int row = tid >> 4;                 // 0..31, 16 threads per row
    int c0 = (tid & 15) * 16;           // 16 consecutive cols per thread
    size_t grow = (size_t)i0 + row;
    float invL = 1.0f / (Lsum_lds[row] + (float)M_);
    const float* hfp = Hf + grow * D_ + c0;
    const float* rvp = Rv + c0;
    const float* crp = &Cred[row][c0];
#pragma unroll
    for (int g = 0; g < 4; ++g) {
      float4 cv = *(const float4*)(crp + g * 4);
      float4 rv = *(const float4*)(rvp + g * 4);
      float4 hv = *(const float4*)(hfp + g * 4);
      float v0 = fmaf(cv.x + rv.x, invL, hv.x);
      float v1 = fmaf(cv.y + rv.y, invL, hv.y);
      float v2 = fmaf(cv.z + rv.z, invL, hv.z);
      float v3 = fmaf(cv.w + rv.w, invL, hv.w);
      *(uint32_t*)&attn[row][c0 + g * 4]     = hpack(v0, v1);
      *(uint32_t*)&attn[row][c0 + g * 4 + 2] = hpack(v2, v3);
    }
  }
  __syncthreads();

  // ---- Phase 3b: out = relu(attn @ Wt^T + bt). 8 waves = 2 rt x 4 cq.
  {
    int rt = w & 1, cq = w >> 1;        // rows rt*16.., cols cq*64..
    f32x4 facc[4];
#pragma unroll
    for (int n = 0; n < 4; ++n) facc[n] = (f32x4){0.f, 0.f, 0.f, 0.f};
    const unsigned short* wwave = WtP + (size_t)(cq * 4) * 512 + (size_t)lane * 8;
#pragma unroll
    for (int kf = 0; kf < 8; ++kf) {
      half8 af = *(const half8*)&attn[rt * 16 + m][kf * 32 + q * 8];
#pragma unroll
      for (int n = 0; n < 4; ++n) {
        half8 bf = *(const half8*)(wwave + ((size_t)kf * 16 + n) * 512);
        facc[n] = __builtin_amdgcn_mfma_f32_16x16x32_f16(af, bf, facc[n], 0, 0, 0);
      }
    }
#pragma unroll
    for (int n = 0; n < 4; ++n) {
      int col = cq * 64 + n * 16 + m;
      float b = bt[col];
#pragma unroll
      for (int r = 0; r < 4; ++r) {
        size_t row = (size_t)i0 + rt * 16 + q * 4 + r;
        out[row * O_ + col] = fmaxf(facc[n][r] + b, 0.0f);
      }
    }
  }
}

// ---------------------------------------------------------------------------
extern "C" void kernel_launch(void* const* d_in, const int* in_sizes, int n_in,
                              void* d_out, int out_size, void* d_ws, size_t ws_size,
                              hipStream_t stream) {
  const float* Hf  = (const float*)d_in[0];  // [N,D]
  const float* Hc  = (const float*)d_in[1];  // [M,D]
  const float* adj = (const float*)d_in[2];  // [N,M]
  const float* wa  = (const float*)d_in[3];  // [2D]
  const float* ba  = (const float*)d_in[4];  // [1]
  const float* Wt  = (const float*)d_in[5];  // [O,D]
  const float* bt  = (const float*)d_in[6];  // [O]
  float* out = (float*)d_out;

  char* ws = (char*)d_ws;
  float* tv   = (float*)(ws + WS_T);
  float* uv   = (float*)(ws + WS_U);
  float* Rv   = (float*)(ws + WS_R);
  unsigned short* WtP = (unsigned short*)(ws + WS_WTP);
  unsigned short* BP  = (unsigned short*)(ws + WS_BP);

  hipMemsetAsync(Rv, 0, D_ * sizeof(float), stream);  // atomic target

  prep_kernel<<<5408, 256, 0, stream>>>(Hf, Hc, wa, ba, Wt, tv, uv, BP, WtP, Rv);
  mega_kernel<<<512, 512, 0, stream>>>(adj, BP, tv, uv, Rv, Hf, WtP, bt, out);
}

// Round 7
// 430.919 us; speedup vs baseline: 1.0246x; 1.0246x over previous
//
#include <hip/hip_runtime.h>
#include <hip/hip_fp16.h>
#include <stdint.h>

// Problem constants (fixed by the reference)
#define N_ 16384
#define M_ 4096
#define D_ 256
#define O_ 256

// Workspace layout (bytes), total ~2.3 MB
#define WS_T    0          // float[N]      exp(sf+ba)     64 KB
#define WS_U    65536      // float[M]      exp(sc)        16 KB
#define WS_R    81920      // float[D]      colsum(Hc)      1 KB
#define WS_WTP  98304      // ushort        Wt packed f16 128 KB
#define WS_BP   229376     // ushort        Hc packed f16   2 MB

typedef float  f32x4  __attribute__((ext_vector_type(4)));
typedef _Float16 half8 __attribute__((ext_vector_type(8)));

// fp32 -> f16 bits (RNE)
__device__ __forceinline__ unsigned short f2h(float f) {
  __half h = __float2half(f);
  unsigned short u;
  __builtin_memcpy(&u, &h, 2);
  return u;
}
// pack two fp32 -> f16x2 bits
__device__ __forceinline__ uint32_t hpack(float a, float b) {
  __half2 h = __floats2half2_rn(a, b);
  uint32_t u;
  __builtin_memcpy(&u, &h, 4);
  return u;
}

// ---------------------------------------------------------------------------
// Merged prep (unchanged): blocks [0,4096) rowdot(Hf)->tv, [4096,5120)
// rowdot(Hc)->uv, [5120,5376) hc_pack, [5376,5408) wt_pack.
__global__ __launch_bounds__(256) void prep_kernel(
    const float* __restrict__ Hf, const float* __restrict__ Hc,
    const float* __restrict__ wa, const float* __restrict__ ba,
    const float* __restrict__ Wt, float* __restrict__ tv,
    float* __restrict__ uv, unsigned short* __restrict__ BP,
    unsigned short* __restrict__ WtP, float* __restrict__ Rv) {
  __shared__ float tile[64][65];
  __shared__ float red[4][64];
  int b = blockIdx.x;
  int t = threadIdx.x;
  if (b < 5120) {
    int wv = t >> 6, lane = t & 63;
    const float* X; const float* w; const float* bias; float* outv; int row;
    if (b < 4096) { X = Hf; w = wa;      bias = ba;      outv = tv; row = b * 4 + wv; }
    else          { X = Hc; w = wa + D_; bias = nullptr; outv = uv; row = (b - 4096) * 4 + wv; }
    const float4* x4 = (const float4*)(X + (size_t)row * D_);
    const float4* w4 = (const float4*)w;
    float4 xa = x4[lane], wa4 = w4[lane];
    float s = xa.x * wa4.x + xa.y * wa4.y + xa.z * wa4.z + xa.w * wa4.w;
#pragma unroll
    for (int off = 32; off > 0; off >>= 1) s += __shfl_xor(s, off);
    if (lane == 0) outv[row] = expf(s + (bias ? bias[0] : 0.0f));
  } else if (b < 5376) {
    int bb = b - 5120;
    int bk = bb >> 2;   // 64 tiles along M (k)
    int bc = bb & 3;    // 4 tiles along D (col)
    int k0 = bk * 64, col0 = bc * 64;
    int lane = t & 63, wv = t >> 6;
    int m = lane & 15, q = lane >> 4;
    float colsum = 0.0f;
#pragma unroll
    for (int i = 0; i < 16; ++i) {
      int e = t + 256 * i;
      int kk = e >> 6, cc = e & 63;
      float v = Hc[(size_t)(k0 + kk) * D_ + col0 + cc];
      tile[kk][cc] = v;
      colsum += v;
    }
    red[wv][t & 63] = colsum;
    __syncthreads();
    if (t < 64)
      atomicAdd(&Rv[col0 + t], red[0][t] + red[1][t] + red[2][t] + red[3][t]);
#pragma unroll
    for (int t8 = 0; t8 < 2; ++t8) {
      int tile_id = t8 * 4 + wv;
      int sub = tile_id >> 2, g = tile_id & 3;
      int kgg = bk * 2 + sub;
      int cgg = bc * 4 + g;
      unsigned short v8[8];
#pragma unroll
      for (int j = 0; j < 8; ++j)
        v8[j] = f2h(tile[sub * 32 + q * 8 + j][g * 16 + m]);
      *(uint4*)(BP + ((size_t)(kgg * 16 + cgg) * 64 + lane) * 8) = *(uint4*)v8;
    }
  } else {
    int tt = (b - 5376) * 256 + t;    // 0..8191
    int lane = tt & 63, cg = (tt >> 6) & 15, kg = tt >> 10;
    int m = lane & 15, q = lane >> 4;
    const float* src = Wt + (size_t)(cg * 16 + m) * D_ + kg * 32 + q * 8;
    float4 w0 = *(const float4*)src, w1 = *(const float4*)(src + 4);
    unsigned short v8[8];
    v8[0] = f2h(w0.x); v8[1] = f2h(w0.y); v8[2] = f2h(w0.z); v8[3] = f2h(w0.w);
    v8[4] = f2h(w1.x); v8[5] = f2h(w1.y); v8[6] = f2h(w1.z); v8[7] = f2h(w1.w);
    *(uint4*)(WtP + (size_t)tt * 8) = *(uint4*)v8;
  }
}

// ---------------------------------------------------------------------------
// Build an f16 MFMA A-fragment from 8 adj bits: slot j = bit_j ? (t*u_j - 1) : 0.
// One v_pk_fma_f16 per pair; mask via BFE/BFI idioms; 0x0000 mask = exact +0.
__device__ __forceinline__ half8 frag_f16(uint32_t bits, __half2 th,
                                          const __half2* up, __half2 mone) {
  union { half8 h; uint32_t u[4]; } r;
#pragma unroll
  for (int p = 0; p < 4; ++p) {
    __half2 v = __hfma2(th, up[p], mone);
    uint32_t c;
    __builtin_memcpy(&c, &v, 4);
    uint32_t mlo = (uint32_t)((int32_t)(bits << (31 - 2 * p)) >> 31);
    uint32_t mhi = (uint32_t)((int32_t)(bits << (30 - 2 * p)) >> 31);
    r.u[p] = c & ((mlo & 0x0000FFFFu) | (mhi & 0xFFFF0000u));   // v_bfi
  }
  return r.h;
}

// issue global loads of one adj chunk (4 rows x 256 cols) into na* regs
#define LOADS(KB)                                                             \
  _Pragma("unroll")                                                           \
  for (int cc = 0; cc < 4; ++cc) {                                            \
    na0[cc] = ar[(size_t)0 * M_ + (KB) + cc * 64 + lane];                     \
    na1[cc] = ar[(size_t)1 * M_ + (KB) + cc * 64 + lane];                     \
    na2[cc] = ar[(size_t)2 * M_ + (KB) + cc * 64 + lane];                     \
    na3[cc] = ar[(size_t)3 * M_ + (KB) + cc * 64 + lane];                     \
  }

// ballot-pack na* into bits_lds[BUF], accumulate su/sc (exact Lsum parts)
#define TAIL(BUF, KB)                                                         \
  {                                                                           \
    unsigned long long bal0[4], bal1[4], bal2[4], bal3[4];                    \
    _Pragma("unroll")                                                         \
    for (int cc = 0; cc < 4; ++cc) {                                          \
      float uvv = u_lds[(KB) + cc * 64 + lane];                               \
      bal0[cc] = __ballot(na0[cc] != 0.0f);                                   \
      bal1[cc] = __ballot(na1[cc] != 0.0f);                                   \
      bal2[cc] = __ballot(na2[cc] != 0.0f);                                   \
      bal3[cc] = __ballot(na3[cc] != 0.0f);                                   \
      su[0] = fmaf(na0[cc], uvv, su[0]);                                      \
      su[1] = fmaf(na1[cc], uvv, su[1]);                                      \
      su[2] = fmaf(na2[cc], uvv, su[2]);                                      \
      su[3] = fmaf(na3[cc], uvv, su[3]);                                      \
    }                                                                         \
    sc[0] += (na0[0] + na0[1]) + (na0[2] + na0[3]);                           \
    sc[1] += (na1[0] + na1[1]) + (na1[2] + na1[3]);                           \
    sc[2] += (na2[0] + na2[1]) + (na2[2] + na2[3]);                           \
    sc[3] += (na3[0] + na3[1]) + (na3[2] + na3[3]);                           \
    if (lane < 32) {                                                          \
      int rowsel = lane >> 3, ccs = (lane >> 1) & 3, hi = lane & 1;           \
      unsigned long long v0 = ccs == 0 ? bal0[0] : ccs == 1 ? bal0[1] : ccs == 2 ? bal0[2] : bal0[3]; \
      unsigned long long v1 = ccs == 0 ? bal1[0] : ccs == 1 ? bal1[1] : ccs == 2 ? bal1[2] : bal1[3]; \
      unsigned long long v2 = ccs == 0 ? bal2[0] : ccs == 1 ? bal2[1] : ccs == 2 ? bal2[2] : bal2[3]; \
      unsigned long long v3 = ccs == 0 ? bal3[0] : ccs == 1 ? bal3[1] : ccs == 2 ? bal3[2] : bal3[3]; \
      unsigned long long v = rowsel == 0 ? v0 : rowsel == 1 ? v1 : rowsel == 2 ? v2 : v3; \
      bits_lds[BUF][w * 4 + rowsel][ccs * 2 + hi] =                           \
          hi ? (unsigned int)(v >> 32) : (unsigned int)v;                     \
    }                                                                         \
  }

// compute one chunk (8 kg; this wave owns kgc = ks*4..ks*4+3, 8 cg of cgh)
#define COMPUTE(C, BUF)                                                       \
  _Pragma("unroll")                                                           \
  for (int kk = 0; kk < 4; ++kk) {                                            \
    int kgc = ks * 4 + kk, kg = (C) * 8 + kgc;                                \
    uint32_t b32 = bits_lds[BUF][rt * 16 + m][kgc];                           \
    uint4 uu = *(const uint4*)&u_h2[kg * 16 + q * 4];                         \
    const unsigned short* bp = BP + ((size_t)(kg * 16 + cgh * 8)) * 512 + (size_t)lane * 8; \
    half8 bf0 = *(const half8*)(bp);                                          \
    half8 bf1 = *(const half8*)(bp + 512);                                    \
    half8 bf2 = *(const half8*)(bp + 1024);                                   \
    half8 bf3 = *(const half8*)(bp + 1536);                                   \
    half8 bf4 = *(const half8*)(bp + 2048);                                   \
    half8 bf5 = *(const half8*)(bp + 2560);                                   \
    half8 bf6 = *(const half8*)(bp + 3072);                                   \
    half8 bf7 = *(const half8*)(bp + 3584);                                   \
    __half2 up[4];                                                            \
    __builtin_memcpy(up, &uu, 16);                                            \
    half8 af = frag_f16((b32 >> sh) & 0xffu, th, up, mone);                   \
    acc[0] = __builtin_amdgcn_mfma_f32_16x16x32_f16(af, bf0, acc[0], 0, 0, 0); \
    acc[1] = __builtin_amdgcn_mfma_f32_16x16x32_f16(af, bf1, acc[1], 0, 0, 0); \
    acc[2] = __builtin_amdgcn_mfma_f32_16x16x32_f16(af, bf2, acc[2], 0, 0, 0); \
    acc[3] = __builtin_amdgcn_mfma_f32_16x16x32_f16(af, bf3, acc[3], 0, 0, 0); \
    acc[4] = __builtin_amdgcn_mfma_f32_16x16x32_f16(af, bf4, acc[4], 0, 0, 0); \
    acc[5] = __builtin_amdgcn_mfma_f32_16x16x32_f16(af, bf5, acc[5], 0, 0, 0); \
    acc[6] = __builtin_amdgcn_mfma_f32_16x16x32_f16(af, bf6, acc[6], 0, 0, 0); \
    acc[7] = __builtin_amdgcn_mfma_f32_16x16x32_f16(af, bf7, acc[7], 0, 0, 0); \
  }

// ---------------------------------------------------------------------------
// Mega kernel v5: chunk-pipelined adj streaming fused INTO the K-loop.
// R6 lesson: 2 blocks/CU run in lockstep -> no cross-block phase overlap;
// profile stayed {VALU 27%, MFMA 9%, HBM 14%} = ~60% idle. Fix: overlap
// within the block. K processed in 16 chunks of 256; per iteration:
//   issue 16 global loads (chunk c+1) -> compute chunk c (bits in LDS,
//   4 kg x [1 frag build + 8 MFMA]) -> ballot+Lsum-fma+bits-write (c+1)
//   -> one barrier. adj HBM latency hides under MFMA/VALU of chunk c.
// Waves: 8 = 2 rt x 2 cgh x 2 ks; A-fragment built once per (rt,kg) per
// cgh (2x redundancy, was 4x); acc = 8 f32x4 = 32 AGPR -> ~70 VGPR live.
// Arithmetic identical to R6 (same ballots/f16 path/f32 Cred planes).
// LDS: bits 2x32x9 u32 2.3K | u_f32 16K | u_h2 8K | Cred[32][260] 33.3K |
//      Lsum 128B = 58.9K -> 2 blocks/CU.
__global__ __launch_bounds__(512, 4) void mega_kernel(
    const float* __restrict__ adj, const unsigned short* __restrict__ BP,
    const float* __restrict__ tv, const float* __restrict__ uv,
    const float* __restrict__ Rv, const float* __restrict__ Hf,
    const unsigned short* __restrict__ WtP, const float* __restrict__ bt,
    float* __restrict__ out) {
  __shared__ __align__(16) char smem[60288];
  unsigned int (*bits_lds)[32][9] = (unsigned int (*)[32][9])(smem);  //  2304 B
  float* u_lds = (float*)(smem + 2304);                               // 16384 B
  uint32_t* u_h2 = (uint32_t*)(smem + 18688);                         //  8192 B
  float (*Cred)[260] = (float (*)[260])(smem + 26880);                // 33280 B
  float* Lsum_lds = (float*)(smem + 60160);                           //   128 B
  unsigned short (*attn)[264] = (unsigned short (*)[264])(smem);      // 16896 B (aliases bits+u_lds, dead by then)

  int tid = threadIdx.x;
  int w = tid >> 6, lane = tid & 63;
  int q = lane >> 4, m = lane & 15;
  int rt = w & 1, cgh = (w >> 1) & 1, ks = w >> 2;
  int sh = q * 8;
  int i0 = blockIdx.x * 32;

  const float* ar = adj + ((size_t)i0 + w * 4) * M_;
  float su[4] = {0.f, 0.f, 0.f, 0.f}, sc[4] = {0.f, 0.f, 0.f, 0.f};
  float na0[4], na1[4], na2[4], na3[4];

  // chunk-0 loads issued first (overlap the u-table fill)
  LOADS(0)

  // u: f32 copy (stream fmas) + packed half2 copy (frag builds)
  for (int i = tid; i < M_ / 2; i += 512) {
    float2 u2 = *(const float2*)(uv + 2 * i);
    u_lds[2 * i] = u2.x; u_lds[2 * i + 1] = u2.y;
    u_h2[i] = hpack(u2.x, u2.y);
  }

  __half2 th = __float2half2_rn(tv[i0 + rt * 16 + m]);
  const __half2 mone = __float2half2_rn(-1.0f);

  f32x4 acc[8];
#pragma unroll
  for (int n = 0; n < 8; ++n) acc[n] = (f32x4){0.f, 0.f, 0.f, 0.f};

  __syncthreads();   // u ready
  TAIL(0, 0)         // chunk 0 -> buf 0
  __syncthreads();   // bits buf0 ready

#pragma unroll 1
  for (int c = 0; c < 16; ++c) {
    if (c < 15) { LOADS((c + 1) * 256) }          // prefetch next chunk
    COMPUTE(c, c & 1)                             // MFMA on current bits
    if (c < 15) { TAIL((c + 1) & 1, (c + 1) * 256) }
    __syncthreads();
  }

  // Lsum (exact): per-row t*sum(adj*u) - sum(adj)
#pragma unroll
  for (int off = 32; off > 0; off >>= 1) {
    su[0] += __shfl_xor(su[0], off); sc[0] += __shfl_xor(sc[0], off);
    su[1] += __shfl_xor(su[1], off); sc[1] += __shfl_xor(sc[1], off);
    su[2] += __shfl_xor(su[2], off); sc[2] += __shfl_xor(sc[2], off);
    su[3] += __shfl_xor(su[3], off); sc[3] += __shfl_xor(sc[3], off);
  }
  if (lane == 0) {
#pragma unroll
    for (int j = 0; j < 4; ++j)
      Lsum_lds[w * 4 + j] = tv[i0 + w * 4 + j] * su[j] - sc[j];
  }

  // ---- Phase 2: sequential ks-plane reduction into fp32 Cred (exact)
#pragma unroll
  for (int s4 = 0; s4 < 2; ++s4) {
    if (ks == s4) {
#pragma unroll
      for (int g = 0; g < 8; ++g) {
        int col = (cgh * 8 + g) * 16 + m;
#pragma unroll
        for (int r = 0; r < 4; ++r) {
          int rl = rt * 16 + q * 4 + r;   // C/D: row=(lane>>4)*4+reg
          if (s4 == 0) Cred[rl][col] = acc[g][r];
          else         Cred[rl][col] += acc[g][r];
        }
      }
    }
    __syncthreads();
  }

  // ---- Phase 3a: attn = (Cred + R)/(Lsum + M) + Hf -> f16 LDS
  {
    int row = tid >> 4;                 // 0..31, 16 threads per row
    int c0 = (tid & 15) * 16;           // 16 consecutive cols per thread
    size_t grow = (size_t)i0 + row;
    float invL = 1.0f / (Lsum_lds[row] + (float)M_);
    const float* hfp = Hf + grow * D_ + c0;
    const float* rvp = Rv + c0;
    const float* crp = &Cred[row][c0];
#pragma unroll
    for (int g = 0; g < 4; ++g) {
      float4 cv = *(const float4*)(crp + g * 4);
      float4 rv = *(const float4*)(rvp + g * 4);
      float4 hv = *(const float4*)(hfp + g * 4);
      float v0 = fmaf(cv.x + rv.x, invL, hv.x);
      float v1 = fmaf(cv.y + rv.y, invL, hv.y);
      float v2 = fmaf(cv.z + rv.z, invL, hv.z);
      float v3 = fmaf(cv.w + rv.w, invL, hv.w);
      *(uint32_t*)&attn[row][c0 + g * 4]     = hpack(v0, v1);
      *(uint32_t*)&attn[row][c0 + g * 4 + 2] = hpack(v2, v3);
    }
  }
  __syncthreads();

  // ---- Phase 3b: out = relu(attn @ Wt^T + bt). 8 waves = 2 rt2 x 4 cq.
  {
    int rt2 = w & 1, cq = w >> 1;       // rows rt2*16.., cols cq*64..
    f32x4 facc[4];
#pragma unroll
    for (int n = 0; n < 4; ++n) facc[n] = (f32x4){0.f, 0.f, 0.f, 0.f};
    const unsigned short* wwave = WtP + (size_t)(cq * 4) * 512 + (size_t)lane * 8;
#pragma unroll
    for (int kf = 0; kf < 8; ++kf) {
      half8 af = *(const half8*)&attn[rt2 * 16 + m][kf * 32 + q * 8];
#pragma unroll
      for (int n = 0; n < 4; ++n) {
        half8 bf = *(const half8*)(wwave + ((size_t)kf * 16 + n) * 512);
        facc[n] = __builtin_amdgcn_mfma_f32_16x16x32_f16(af, bf, facc[n], 0, 0, 0);
      }
    }
#pragma unroll
    for (int n = 0; n < 4; ++n) {
      int col = cq * 64 + n * 16 + m;
      float b = bt[col];
#pragma unroll
      for (int r = 0; r < 4; ++r) {
        size_t row = (size_t)i0 + rt2 * 16 + q * 4 + r;
        out[row * O_ + col] = fmaxf(facc[n][r] + b, 0.0f);
      }
    }
  }
}

// ---------------------------------------------------------------------------
extern "C" void kernel_launch(void* const* d_in, const int* in_sizes, int n_in,
                              void* d_out, int out_size, void* d_ws, size_t ws_size,
                              hipStream_t stream) {
  const float* Hf  = (const float*)d_in[0];  // [N,D]
  const float* Hc  = (const float*)d_in[1];  // [M,D]
  const float* adj = (const float*)d_in[2];  // [N,M]
  const float* wa  = (const float*)d_in[3];  // [2D]
  const float* ba  = (const float*)d_in[4];  // [1]
  const float* Wt  = (const float*)d_in[5];  // [O,D]
  const float* bt  = (const float*)d_in[6];  // [O]
  float* out = (float*)d_out;

  char* ws = (char*)d_ws;
  float* tv   = (float*)(ws + WS_T);
  float* uv   = (float*)(ws + WS_U);
  float* Rv   = (float*)(ws + WS_R);
  unsigned short* WtP = (unsigned short*)(ws + WS_WTP);
  unsigned short* BP  = (unsigned short*)(ws + WS_BP);

  hipMemsetAsync(Rv, 0, D_ * sizeof(float), stream);  // atomic target

  prep_kernel<<<5408, 256, 0, stream>>>(Hf, Hc, wa, ba, Wt, tv, uv, BP, WtP, Rv);
  mega_kernel<<<512, 512, 0, stream>>>(adj, BP, tv, uv, Rv, Hf, WtP, bt, out);
}